// Round 7
// baseline (219.357 us; speedup 1.0000x reference)
//
#include <hip/hip_runtime.h>
#include <hip/hip_bf16.h>

#define LLEN 384
#define CDIM 256
#define NH 8
#define HD 32
#define DIN 128
#define LN_EPS 1e-5f
#define SCL 0.17677669529663687f   // 1/sqrt(32)

typedef __attribute__((ext_vector_type(8))) short bh8;
typedef __attribute__((ext_vector_type(4))) float f32x4;
typedef __attribute__((ext_vector_type(4))) unsigned int u32x4;

__device__ __forceinline__ unsigned short f2bf(float f){
  unsigned int u = __float_as_uint(f);
  u += 0x7fffu + ((u >> 16) & 1u);
  return (unsigned short)(u >> 16);
}

// Pack two fp32 -> dword of 2 bf16 (RNE). HW v_cvt_pk_bf16_f32 on gfx950.
__device__ __forceinline__ unsigned int pkbf(float a, float b){
#if defined(__gfx950__) && __has_builtin(__builtin_amdgcn_cvt_pk_bf16_f32)
  typedef __attribute__((ext_vector_type(2))) __bf16 vbf2;
  vbf2 v = __builtin_amdgcn_cvt_pk_bf16_f32(a, b);
  union { vbf2 v; unsigned int u; } cv; cv.v = v; return cv.u;
#else
  return (unsigned int)f2bf(a) | ((unsigned int)f2bf(b) << 16);
#endif
}

// Packed tree-reduce: sum v[0..7] over the 16 lanes of a quad (lane bits 0-3).
// Returns: lane lm holds full sum of v[lm&7].
__device__ __forceinline__ float pk_reduce8(const float* v, int lane){
  bool b0 = lane & 1, b1 = lane & 2, b2 = lane & 4;
  float r0 = (b0 ? v[1] : v[0]) + __shfl_xor(b0 ? v[0] : v[1], 1, 64);
  float r1 = (b0 ? v[3] : v[2]) + __shfl_xor(b0 ? v[2] : v[3], 1, 64);
  float r2 = (b0 ? v[5] : v[4]) + __shfl_xor(b0 ? v[4] : v[5], 1, 64);
  float r3 = (b0 ? v[7] : v[6]) + __shfl_xor(b0 ? v[6] : v[7], 1, 64);
  float s0 = (b1 ? r1 : r0) + __shfl_xor(b1 ? r0 : r1, 2, 64);
  float s1 = (b1 ? r3 : r2) + __shfl_xor(b1 ? r2 : r3, 2, 64);
  float t0 = (b2 ? s1 : s0) + __shfl_xor(b2 ? s0 : s1, 4, 64);
  return t0 + __shfl_xor(t0, 8, 64);
}

// ---------------------------------------------------------------------------
// Pack weights (fp32 row-major [K][N]) into bf16 MFMA B-fragment order.
// ---------------------------------------------------------------------------
__global__ __launch_bounds__(256) void pack_w(
    const float* __restrict__ Wpre, const float* __restrict__ Weq,
    const float* __restrict__ Wek,  const float* __restrict__ Wq,
    const float* __restrict__ Wk,   const float* __restrict__ Wv,
    unsigned short* __restrict__ Pp, unsigned short* __restrict__ Pq,
    unsigned short* __restrict__ Pk, unsigned short* __restrict__ PWq,
    unsigned short* __restrict__ PWk, unsigned short* __restrict__ PWv)
{
  int tid = blockIdx.x * 256 + threadIdx.x;   // 176 blocks * 256 = 45056
  const float* W; unsigned short* P; int base;
  if      (tid <  4096){ W = Wpre; P = Pp;  base = tid;         }
  else if (tid < 12288){ W = Weq;  P = Pq;  base = tid -  4096; }
  else if (tid < 20480){ W = Wek;  P = Pk;  base = tid - 12288; }
  else if (tid < 28672){ W = Wq;   P = PWq; base = tid - 20480; }
  else if (tid < 36864){ W = Wk;   P = PWk; base = tid - 28672; }
  else                 { W = Wv;   P = PWv; base = tid - 36864; }
  int l   = base & 63;
  int c   = (base >> 6) & 15;
  int kc  = base >> 10;
  int krow = kc*32 + (l >> 4)*8;
  int col  = c*16 + (l & 15);
  unsigned int wds[4];
  #pragma unroll
  for (int p = 0; p < 4; p++){
    unsigned short lo = f2bf(W[(size_t)(krow + 2*p    )*CDIM + col]);
    unsigned short hi = f2bf(W[(size_t)(krow + 2*p + 1)*CDIM + col]);
    wds[p] = (unsigned int)lo | ((unsigned int)hi << 16);
  }
  uint4 v; v.x = wds[0]; v.y = wds[1]; v.z = wds[2]; v.w = wds[3];
  *(uint4*)(P + (size_t)base*8) = v;
}

// ---------------------------------------------------------------------------
// qkv: 144 blocks = jb(12, 32-row tiles) x m(3) x nq(4). Doubled CU coverage
// (R14 win, kept). All output addressing from the GLOBAL row.
// ---------------------------------------------------------------------------
__global__ __launch_bounds__(256) void qkv_mfma(
    const float* __restrict__ x3d,
    const float* __restrict__ bq, const float* __restrict__ bk, const float* __restrict__ bv,
    const unsigned short* __restrict__ PWq, const unsigned short* __restrict__ PWk,
    const unsigned short* __restrict__ PWv,
    float* __restrict__ Vm, unsigned short* __restrict__ QmH,
    float* __restrict__ QmT, unsigned short* __restrict__ PKt)
{
  __shared__ __align__(16) unsigned short Xb[32*264];
  const int bx = blockIdx.x;
  const int jb = bx / 12, rem = bx % 12;
  const int m = rem >> 2, nq = rem & 3;
  const int t  = threadIdx.x;
  const int w  = t >> 6, l = t & 63, q4 = l >> 4, lm = l & 15;

  const float* src = x3d + (size_t)jb*32*CDIM;
  #pragma unroll
  for (int it = 0; it < 8; it++){
    int idx = it*256 + t;
    int r = idx >> 6, k4 = (idx & 63) << 2;
    float4 v = *(const float4*)(src + (size_t)r*CDIM + k4);
    ushort4 b;
    b.x = f2bf(v.x); b.y = f2bf(v.y); b.z = f2bf(v.z); b.w = f2bf(v.w);
    *(ushort4*)(&Xb[r*264 + k4]) = b;
  }
  __syncthreads();

  const unsigned short* P = (m == 0) ? PWq : (m == 1) ? PWk : PWv;
  const float* bias       = (m == 0) ? bq  : (m == 1) ? bk  : bv;
  const int cidx = nq*4 + w;          // 16-col chunk this wave owns
  f32x4 acc[2];
  #pragma unroll
  for (int a = 0; a < 2; a++){ f32x4 z = {0.f,0.f,0.f,0.f}; acc[a] = z; }
  #pragma unroll
  for (int kc = 0; kc < 8; kc++){
    bh8 bf = *(const bh8*)(P + ((size_t)(kc*16 + cidx)*64 + l)*8);
    #pragma unroll
    for (int rt = 0; rt < 2; rt++){
      bh8 af = *(const bh8*)(&Xb[(rt*16 + lm)*264 + kc*32 + q4*8]);
      acc[rt] = __builtin_amdgcn_mfma_f32_16x16x32_bf16(af, bf, acc[rt], 0, 0, 0);
    }
  }
  {
    int c = cidx*16 + lm;
    float bb = bias[c];
    #pragma unroll
    for (int rt = 0; rt < 2; rt++)
      #pragma unroll
      for (int rg = 0; rg < 4; rg++){
        int row = jb*32 + rt*16 + q4*4 + rg;
        float v = acc[rt][rg] + bb;
        if (m == 0){
          QmH[(size_t)row*CDIM + c] = f2bf(v);
          // tiled-coalesced Q^T: group = row>>2, innermost = rg
          QmT[(((size_t)(row >> 2))*CDIM + c)*4 + rg] = v;
        } else if (m == 1){
          int kc2 = c >> 5;            // head
          int jj2 = c & 7;
          int l2  = ((c >> 3) & 3)*16 + (row & 15);
          PKt[(((size_t)kc2*24 + (row >> 4))*64 + l2)*8 + jj2] = f2bf(v);
        } else {
          Vm[(size_t)row*CDIM + c] = v;
        }
      }
  }
}

// ---------------------------------------------------------------------------
// Main tile kernel: one block per (i, j-tile). 2304 blocks. R13 body exactly
// (81.5 us proven). R15: setprio REMOVED — it fenced the compiler's cross-
// iteration load pipelining in the kc loops (VGPR 84->72, MfmaUtil 25.7->19.5,
// dur +23us). T5 is confirmed negative for this barrier-lockstep structure.
// ---------------------------------------------------------------------------
__global__ __launch_bounds__(256, 3) void x3d_tiles(
  const float* __restrict__ x2d,
  const float* __restrict__ bpre, const float* __restrict__ ln_g, const float* __restrict__ ln_b,
  const float* __restrict__ beq,  const float* __restrict__ bek,
  const float* __restrict__ QmT,  const unsigned short* __restrict__ QmH,
  const unsigned short* __restrict__ PKt,
  const unsigned short* __restrict__ Pp, const unsigned short* __restrict__ Pq,
  const unsigned short* __restrict__ Pk,
  float* __restrict__ Sg, float* __restrict__ x2part)
{
  // EX holds X as fp32 (64x128, swizzled 16B blocks, 32768 B) during GEMM1,
  // then E as bf16 (64x264 shorts, 33792 B) for GEMM2/3.
  __shared__ __align__(16) unsigned short EX[64*264];      // 33792 B
  __shared__ float rowstat[4][64][2];                      //  2048 B
  __shared__ float muS[64], istdS[64];                     //   512 B
  __shared__ float bpreS[CDIM], gS[CDIM], bSh[CDIM], beqS[CDIM], bekS[CDIM]; // 5120 B
  __shared__ float qk1S[NH*64];                            //  2048 B

  const int bx = blockIdx.x;
  const int i = bx / 6, jt = bx % 6, j0 = jt * 64;
  const int t = threadIdx.x;
  const int w = t >> 6, l = t & 63, q4 = l >> 4, lm = l & 15;
  const int wbase = w << 6;

  // ---- qk1 fragment loads FIRST (oldest in vmcnt queue) ----
  bh8 aqv[2], kf[2][4];
  #pragma unroll
  for (int hh = 0; hh < 2; hh++){
    int h = 2*w + hh;
    aqv[hh] = *(const bh8*)(QmH + (size_t)i*CDIM + h*HD + q4*8);
    #pragma unroll
    for (int ct = 0; ct < 4; ct++)
      kf[hh][ct] = *(const bh8*)(PKt + (((size_t)h*24 + (jt*4 + ct))*64 + l)*8);
  }

  // ---- async stage x2d tile (64x128 fp32, 32 KB) direct to LDS ----
  // LDS block P (16B) = w*512 + it*64 + l; row = P>>5, pb = P&31;
  // global source block = pb ^ (row&7)  (XOR swizzle on the global side).
  {
    const char* gtile = (const char*)(x2d + ((size_t)i*LLEN + j0)*DIN);
    #pragma unroll
    for (int it = 0; it < 8; it++){
      int P   = w*512 + it*64 + l;
      int row = P >> 5;
      int blk = (P & 31) ^ (row & 7);
      const void* gp = gtile + ((size_t)row*512 + ((size_t)blk << 4));
      unsigned short* lp = EX + (w*4096 + it*512);
      __builtin_amdgcn_global_load_lds(
          (const __attribute__((address_space(1))) void*)gp,
          (__attribute__((address_space(3))) void*)lp, 16, 0, 0);
    }
  }

  // ---- qk1 MFMAs (wait only on their own loads; staging stays in flight) ----
  #pragma unroll
  for (int hh = 0; hh < 2; hh++){
    int h = 2*w + hh;
    #pragma unroll
    for (int ct = 0; ct < 4; ct++){
      f32x4 z = {0.f,0.f,0.f,0.f};
      f32x4 a1 = __builtin_amdgcn_mfma_f32_16x16x32_bf16(aqv[hh], kf[hh][ct], z, 0, 0, 0);
      if (q4 == 0) qk1S[h*64 + ct*16 + lm] = a1[0];
    }
  }

  bpreS[t] = bpre[t]; gS[t] = ln_g[t]; bSh[t] = ln_b[t];
  beqS[t]  = beq[t];  bekS[t] = bek[t];
  __syncthreads();   // drains staging too

  // ---- GEMM1: Epre = X @ Wpre (fp32 LDS reads + cvt) ----
  const float* XF = (const float*)EX;
  f32x4 acc[4][4];
  #pragma unroll
  for (int a = 0; a < 4; a++)
    #pragma unroll
    for (int b = 0; b < 4; b++){ f32x4 z = {0.f,0.f,0.f,0.f}; acc[a][b] = z; }
  #pragma unroll
  for (int kc = 0; kc < 4; kc++){
    bh8 af[4];
    #pragma unroll
    for (int rt = 0; rt < 4; rt++){
      int row = rt*16 + lm;
      int sw  = row & 7;
      int blk0 = kc*8 + q4*2;
      f32x4 a0 = *(const f32x4*)(XF + row*128 + ((blk0       ^ sw) << 2));
      f32x4 a1 = *(const f32x4*)(XF + row*128 + (((blk0 + 1) ^ sw) << 2));
      union { unsigned int u[4]; bh8 v; } cv;
      cv.u[0] = pkbf(a0[0], a0[1]); cv.u[1] = pkbf(a0[2], a0[3]);
      cv.u[2] = pkbf(a1[0], a1[1]); cv.u[3] = pkbf(a1[2], a1[3]);
      af[rt] = cv.v;
    }
    #pragma unroll
    for (int ct = 0; ct < 4; ct++){
      bh8 bf = *(const bh8*)(Pp + ((size_t)(kc*16 + (w*4 + ct))*64 + l)*8);
      #pragma unroll
      for (int rt = 0; rt < 4; rt++)
        acc[rt][ct] = __builtin_amdgcn_mfma_f32_16x16x32_bf16(af[rt], bf, acc[rt][ct], 0, 0, 0);
    }
  }

  // ---- + bpre, per-row LN stats via packed tree-reduce ----
  #pragma unroll
  for (int rt = 0; rt < 4; rt++){
    float v[8];   // v[2rg+0]=sum partial, v[2rg+1]=sq partial
    #pragma unroll
    for (int p = 0; p < 8; p++) v[p] = 0.f;
    #pragma unroll
    for (int ct = 0; ct < 4; ct++){
      float bb = bpreS[wbase + ct*16 + lm];
      #pragma unroll
      for (int rg = 0; rg < 4; rg++){
        float x = acc[rt][ct][rg] + bb;
        acc[rt][ct][rg] = x;
        v[2*rg]   += x;
        v[2*rg+1] += x*x;
      }
    }
    float red = pk_reduce8(v, lm);
    if (lm < 8){
      int p = lm;                       // p = 2rg+which
      rowstat[w][rt*16 + q4*4 + (p >> 1)][p & 1] = red;
    }
  }
  __syncthreads();
  if (t < 64){
    float s  = rowstat[0][t][0] + rowstat[1][t][0] + rowstat[2][t][0] + rowstat[3][t][0];
    float s2 = rowstat[0][t][1] + rowstat[1][t][1] + rowstat[2][t][1] + rowstat[3][t][1];
    float mu = s * (1.f/256.f);
    float var = s2 * (1.f/256.f) - mu*mu;
    muS[t] = mu;
    istdS[t] = rsqrtf(var + LN_EPS);
  }
  __syncthreads();

  // ---- LN + ReLU -> bf16 E tile (stride 264, overwrites X) ----
  #pragma unroll
  for (int rt = 0; rt < 4; rt++){
    #pragma unroll
    for (int rg = 0; rg < 4; rg++){
      int row = rt*16 + q4*4 + rg;
      float mu = muS[row], is = istdS[row];
      #pragma unroll
      for (int ct = 0; ct < 4; ct++){
        int c = wbase + ct*16 + lm;
        float v = (acc[rt][ct][rg] - mu)*is*gS[c] + bSh[c];
        v = fmaxf(v, 0.f);
        EX[row*264 + c] = f2bf(v);
      }
    }
  }
  __syncthreads();

  // ---- GEMM2: EFK = E @ Wek ----
  #pragma unroll
  for (int a = 0; a < 4; a++)
    #pragma unroll
    for (int b = 0; b < 4; b++){ f32x4 z = {0.f,0.f,0.f,0.f}; acc[a][b] = z; }
  #pragma unroll
  for (int kc = 0; kc < 8; kc++){
    bh8 af[4];
    #pragma unroll
    for (int rt = 0; rt < 4; rt++)
      af[rt] = *(const bh8*)(&EX[(rt*16 + lm)*264 + kc*32 + q4*8]);
    #pragma unroll
    for (int ct = 0; ct < 4; ct++){
      bh8 bf = *(const bh8*)(Pk + ((size_t)(kc*16 + (w*4 + ct))*64 + l)*8);
      #pragma unroll
      for (int rt = 0; rt < 4; rt++)
        acc[rt][ct] = __builtin_amdgcn_mfma_f32_16x16x32_bf16(af[rt], bf, acc[rt][ct], 0, 0, 0);
    }
  }

  // ---- scores: term2 packed-reduce + qk1 + scale; keep in screg ----
  float screg[4];
  #pragma unroll
  for (int rt = 0; rt < 4; rt++){
    float v[8];   // v[2rg+which]
    #pragma unroll
    for (int p = 0; p < 8; p++) v[p] = 0.f;
    #pragma unroll
    for (int ct = 0; ct < 4; ct++){
      int c = wbase + ct*16 + lm;
      float bek_ = bekS[c];
      // tiled-coalesced Q^T read: group = jt*16 + rt*4 + q4, 4 j's contiguous
      float4 qv = *(const float4*)(QmT + (((size_t)jt*16 + rt*4 + q4)*CDIM + c)*4);
      int wh = ct >> 1;
      v[0 + wh] += (acc[rt][ct][0] + bek_) * qv.x;
      v[2 + wh] += (acc[rt][ct][1] + bek_) * qv.y;
      v[4 + wh] += (acc[rt][ct][2] + bek_) * qv.z;
      v[6 + wh] += (acc[rt][ct][3] + bek_) * qv.w;
    }
    float red = pk_reduce8(v, lm);
    int p = lm & 7;                     // p = 2rg + which
    int jloc = rt*16 + q4*4 + (p >> 1);
    float sc = (red + qk1S[(2*w + (p & 1))*64 + jloc]) * SCL;
    screg[rt] = sc;
    if (lm < 8)
      Sg[((size_t)i*NH + 2*w + (p & 1))*LLEN + j0 + jloc] = sc;
  }

  // ---- GEMM3: EFQ = E @ Weq ----
  #pragma unroll
  for (int a = 0; a < 4; a++)
    #pragma unroll
    for (int b = 0; b < 4; b++){ f32x4 z = {0.f,0.f,0.f,0.f}; acc[a][b] = z; }
  #pragma unroll
  for (int kc = 0; kc < 8; kc++){
    bh8 af[4];
    #pragma unroll
    for (int rt = 0; rt < 4; rt++)
      af[rt] = *(const bh8*)(&EX[(rt*16 + lm)*264 + kc*32 + q4*8]);
    #pragma unroll
    for (int ct = 0; ct < 4; ct++){
      bh8 bf = *(const bh8*)(Pq + ((size_t)(kc*16 + (w*4 + ct))*64 + l)*8);
      #pragma unroll
      for (int rt = 0; rt < 4; rt++)
        acc[rt][ct] = __builtin_amdgcn_mfma_f32_16x16x32_bf16(af[rt], bf, acc[rt][ct], 0, 0, 0);
    }
  }

  // ---- x2 partial: x2[h,c] += scores[h,j]*efq[j,c] (pre-softmax scaled) ----
  float x2p[4] = {0.f, 0.f, 0.f, 0.f};
  float bq4[4];
  #pragma unroll
  for (int ct = 0; ct < 4; ct++) bq4[ct] = beqS[wbase + ct*16 + lm];
  #pragma unroll
  for (int rt = 0; rt < 4; rt++){
    float sb[8];
    #pragma unroll
    for (int p = 0; p < 8; p++)
      sb[p] = __shfl(screg[rt], (l & 48) | p, 64);
    #pragma unroll
    for (int ct = 0; ct < 4; ct++){
      int wh = ct >> 1;
      #pragma unroll
      for (int rg = 0; rg < 4; rg++)
        x2p[ct] = fmaf(sb[2*rg + wh], acc[rt][ct][rg] + bq4[ct], x2p[ct]);
    }
  }
  {
    bool b4 = l & 16, b5 = l & 32;
    float r0 = (b4 ? x2p[1] : x2p[0]) + __shfl_xor(b4 ? x2p[0] : x2p[1], 16, 64);
    float r1 = (b4 ? x2p[3] : x2p[2]) + __shfl_xor(b4 ? x2p[2] : x2p[3], 16, 64);
    float q  = (b5 ? r1 : r0) + __shfl_xor(b5 ? r0 : r1, 32, 64);
    int ctq = ((l >> 4) & 1) | (((l >> 5) & 1) << 1);
    x2part[((size_t)jt*LLEN + i)*CDIM + wbase + ctq*16 + lm] = q;
  }
}

// ---------------------------------------------------------------------------
// finish: softmax + x1 + x2 + out-proj. 384 blocks. x1 with 8-deep ILP.
// ---------------------------------------------------------------------------
__global__ __launch_bounds__(256) void finish(
    const float* __restrict__ Sg, const float* __restrict__ x2part,
    const float* __restrict__ Vm, const float* __restrict__ Wo,
    const float* __restrict__ bo, float* __restrict__ out)
{
  __shared__ float scoresS[NH*LLEN];   // 12 KB
  __shared__ float xoutS[CDIM];
  const int i = blockIdx.x;
  const int t = threadIdx.x;

  #pragma unroll
  for (int it = 0; it < 3; it++)
    ((float4*)scoresS)[it*256 + t] = ((const float4*)(Sg + (size_t)i*NH*LLEN))[it*256 + t];
  __syncthreads();

  const int h = t >> 5;
  const int g32 = t & 31;
  float sv[12];
  float mx = -3.0e38f;
  #pragma unroll
  for (int it = 0; it < 12; it++){
    float s = scoresS[h*LLEN + it*32 + g32];
    sv[it] = s;
    mx = fmaxf(mx, s);
  }
  #pragma unroll
  for (int mk = 1; mk < 32; mk <<= 1) mx = fmaxf(mx, __shfl_xor(mx, mk, 64));
  float den = 0.f;
  #pragma unroll
  for (int it = 0; it < 12; it++){ float e = __expf(sv[it] - mx); sv[it] = e; den += e; }
  #pragma unroll
  for (int mk = 1; mk < 32; mk <<= 1) den += __shfl_xor(den, mk, 64);
  float rden = 1.f / den;
  #pragma unroll
  for (int it = 0; it < 12; it++) scoresS[h*LLEN + it*32 + g32] = sv[it]*rden;
  __syncthreads();

  float a[8];
  #pragma unroll
  for (int k = 0; k < 8; k++) a[k] = 0.f;
  {
    const float* vp = Vm + t;
    const float* sp = scoresS + h*LLEN;
    #pragma unroll 2
    for (int j = 0; j < LLEN; j += 8){
      #pragma unroll
      for (int k = 0; k < 8; k++)
        a[k] = fmaf(sp[j+k], vp[(size_t)(j+k)*CDIM], a[k]);
    }
  }
  float x1 = ((a[0]+a[1]) + (a[2]+a[3])) + ((a[4]+a[5]) + (a[6]+a[7]));
  float x2v = 0.f;
  #pragma unroll
  for (int jt = 0; jt < 6; jt++)
    x2v += x2part[((size_t)jt*LLEN + i)*CDIM + t];
  xoutS[t] = x1 + x2v;
  __syncthreads();

  float b0a = bo[t], b1a = 0.f, b2a = 0.f, b3a = 0.f;
  #pragma unroll 4
  for (int c = 0; c < CDIM; c += 4){
    b0a = fmaf(xoutS[c+0], Wo[(size_t)(c+0)*CDIM + t], b0a);
    b1a = fmaf(xoutS[c+1], Wo[(size_t)(c+1)*CDIM + t], b1a);
    b2a = fmaf(xoutS[c+2], Wo[(size_t)(c+2)*CDIM + t], b2a);
    b3a = fmaf(xoutS[c+3], Wo[(size_t)(c+3)*CDIM + t], b3a);
  }
  out[(size_t)i*CDIM + t] = (b0a + b1a) + (b2a + b3a);
}

// ---------------------------------------------------------------------------
extern "C" void kernel_launch(void* const* d_in, const int* in_sizes, int n_in,
                              void* d_out, int out_size, void* d_ws, size_t ws_size,
                              hipStream_t stream)
{
  const float* x2d  = (const float*)d_in[0];
  const float* x3d  = (const float*)d_in[1];
  const float* Wq   = (const float*)d_in[2];
  const float* bq   = (const float*)d_in[3];
  const float* Wk   = (const float*)d_in[4];
  const float* bk   = (const float*)d_in[5];
  const float* Wv   = (const float*)d_in[6];
  const float* bv   = (const float*)d_in[7];
  const float* Wpre = (const float*)d_in[8];
  const float* bpre = (const float*)d_in[9];
  const float* ln_g = (const float*)d_in[10];
  const float* ln_b = (const float*)d_in[11];
  const float* Weq  = (const float*)d_in[12];
  const float* beq  = (const float*)d_in[13];
  const float* Wek  = (const float*)d_in[14];
  const float* bek  = (const float*)d_in[15];
  const float* Wo   = (const float*)d_in[16];
  const float* bo   = (const float*)d_in[17];
  float* out = (float*)d_out;

  float* Vm  = (float*)d_ws;                                 // 384*256 f32
  float* QmT = Vm + LLEN*CDIM;                               // 96*256*4 f32 (tiled Q^T)
  unsigned short* QmH = (unsigned short*)(QmT + CDIM*LLEN);  // 384*256 bf16
  unsigned short* PKt = QmH + LLEN*CDIM;                     // 8*24*64*8 bf16
  unsigned short* Pp  = PKt + LLEN*CDIM;                     // 128*256
  unsigned short* Pq  = Pp  + DIN*CDIM;                      // 256*256
  unsigned short* Pk  = Pq  + CDIM*CDIM;
  unsigned short* PWq = Pk  + CDIM*CDIM;
  unsigned short* PWk = PWq + CDIM*CDIM;
  unsigned short* PWv = PWk + CDIM*CDIM;
  float* Sg     = (float*)(PWv + CDIM*CDIM);                 // 384*8*384 f32
  float* x2part = Sg + (size_t)LLEN*NH*LLEN;                 // 6*384*256 f32

  pack_w<<<dim3(176), dim3(256), 0, stream>>>(Wpre, Weq, Wek, Wq, Wk, Wv,
                                              Pp, Pq, Pk, PWq, PWk, PWv);
  qkv_mfma<<<dim3(144), dim3(256), 0, stream>>>(x3d, bq, bk, bv, PWq, PWk, PWv,
                                                Vm, QmH, QmT, PKt);
  x3d_tiles<<<dim3(LLEN*6), dim3(256), 0, stream>>>(x2d, bpre, ln_g, ln_b, beq, bek,
                                                    QmT, QmH, PKt, Pp, Pq, Pk, Sg, x2part);
  finish<<<dim3(LLEN), dim3(256), 0, stream>>>(Sg, x2part, Vm, Wo, bo, out);
}

// Round 8
// 213.049 us; speedup vs baseline: 1.0296x; 1.0296x over previous
//
#include <hip/hip_runtime.h>
#include <hip/hip_bf16.h>

#define LLEN 384
#define CDIM 256
#define NH 8
#define HD 32
#define DIN 128
#define LN_EPS 1e-5f
#define SCL 0.17677669529663687f   // 1/sqrt(32)

typedef __attribute__((ext_vector_type(8))) short bh8;
typedef __attribute__((ext_vector_type(4))) float f32x4;
typedef __attribute__((ext_vector_type(4))) unsigned int u32x4;

__device__ __forceinline__ unsigned short f2bf(float f){
  unsigned int u = __float_as_uint(f);
  u += 0x7fffu + ((u >> 16) & 1u);
  return (unsigned short)(u >> 16);
}

// Pack two fp32 -> dword of 2 bf16 (RNE). HW v_cvt_pk_bf16_f32 on gfx950.
__device__ __forceinline__ unsigned int pkbf(float a, float b){
#if defined(__gfx950__) && __has_builtin(__builtin_amdgcn_cvt_pk_bf16_f32)
  typedef __attribute__((ext_vector_type(2))) __bf16 vbf2;
  vbf2 v = __builtin_amdgcn_cvt_pk_bf16_f32(a, b);
  union { vbf2 v; unsigned int u; } cv; cv.v = v; return cv.u;
#else
  return (unsigned int)f2bf(a) | ((unsigned int)f2bf(b) << 16);
#endif
}

// Packed tree-reduce: sum v[0..7] over the 16 lanes of a quad (lane bits 0-3).
// Returns: lane lm holds full sum of v[lm&7].
__device__ __forceinline__ float pk_reduce8(const float* v, int lane){
  bool b0 = lane & 1, b1 = lane & 2, b2 = lane & 4;
  float r0 = (b0 ? v[1] : v[0]) + __shfl_xor(b0 ? v[0] : v[1], 1, 64);
  float r1 = (b0 ? v[3] : v[2]) + __shfl_xor(b0 ? v[2] : v[3], 1, 64);
  float r2 = (b0 ? v[5] : v[4]) + __shfl_xor(b0 ? v[4] : v[5], 1, 64);
  float r3 = (b0 ? v[7] : v[6]) + __shfl_xor(b0 ? v[6] : v[7], 1, 64);
  float s0 = (b1 ? r1 : r0) + __shfl_xor(b1 ? r0 : r1, 2, 64);
  float s1 = (b1 ? r3 : r2) + __shfl_xor(b1 ? r2 : r3, 2, 64);
  float t0 = (b2 ? s1 : s0) + __shfl_xor(b2 ? s0 : s1, 4, 64);
  return t0 + __shfl_xor(t0, 8, 64);
}

// ---------------------------------------------------------------------------
// Pack weights (fp32 row-major [K][N]) into bf16 MFMA B-fragment order.
// ---------------------------------------------------------------------------
__global__ __launch_bounds__(256) void pack_w(
    const float* __restrict__ Wpre, const float* __restrict__ Weq,
    const float* __restrict__ Wek,  const float* __restrict__ Wq,
    const float* __restrict__ Wk,   const float* __restrict__ Wv,
    unsigned short* __restrict__ Pp, unsigned short* __restrict__ Pq,
    unsigned short* __restrict__ Pk, unsigned short* __restrict__ PWq,
    unsigned short* __restrict__ PWk, unsigned short* __restrict__ PWv)
{
  int tid = blockIdx.x * 256 + threadIdx.x;   // 176 blocks * 256 = 45056
  const float* W; unsigned short* P; int base;
  if      (tid <  4096){ W = Wpre; P = Pp;  base = tid;         }
  else if (tid < 12288){ W = Weq;  P = Pq;  base = tid -  4096; }
  else if (tid < 20480){ W = Wek;  P = Pk;  base = tid - 12288; }
  else if (tid < 28672){ W = Wq;   P = PWq; base = tid - 20480; }
  else if (tid < 36864){ W = Wk;   P = PWk; base = tid - 28672; }
  else                 { W = Wv;   P = PWv; base = tid - 36864; }
  int l   = base & 63;
  int c   = (base >> 6) & 15;
  int kc  = base >> 10;
  int krow = kc*32 + (l >> 4)*8;
  int col  = c*16 + (l & 15);
  unsigned int wds[4];
  #pragma unroll
  for (int p = 0; p < 4; p++){
    unsigned short lo = f2bf(W[(size_t)(krow + 2*p    )*CDIM + col]);
    unsigned short hi = f2bf(W[(size_t)(krow + 2*p + 1)*CDIM + col]);
    wds[p] = (unsigned int)lo | ((unsigned int)hi << 16);
  }
  uint4 v; v.x = wds[0]; v.y = wds[1]; v.z = wds[2]; v.w = wds[3];
  *(uint4*)(P + (size_t)base*8) = v;
}

// ---------------------------------------------------------------------------
// qkv: 144 blocks = jb(12, 32-row tiles) x m(3) x nq(4).
// ---------------------------------------------------------------------------
__global__ __launch_bounds__(256) void qkv_mfma(
    const float* __restrict__ x3d,
    const float* __restrict__ bq, const float* __restrict__ bk, const float* __restrict__ bv,
    const unsigned short* __restrict__ PWq, const unsigned short* __restrict__ PWk,
    const unsigned short* __restrict__ PWv,
    float* __restrict__ Vm, unsigned short* __restrict__ QmH,
    float* __restrict__ QmT, unsigned short* __restrict__ PKt)
{
  __shared__ __align__(16) unsigned short Xb[32*264];
  const int bx = blockIdx.x;
  const int jb = bx / 12, rem = bx % 12;
  const int m = rem >> 2, nq = rem & 3;
  const int t  = threadIdx.x;
  const int w  = t >> 6, l = t & 63, q4 = l >> 4, lm = l & 15;

  const float* src = x3d + (size_t)jb*32*CDIM;
  #pragma unroll
  for (int it = 0; it < 8; it++){
    int idx = it*256 + t;
    int r = idx >> 6, k4 = (idx & 63) << 2;
    float4 v = *(const float4*)(src + (size_t)r*CDIM + k4);
    ushort4 b;
    b.x = f2bf(v.x); b.y = f2bf(v.y); b.z = f2bf(v.z); b.w = f2bf(v.w);
    *(ushort4*)(&Xb[r*264 + k4]) = b;
  }
  __syncthreads();

  const unsigned short* P = (m == 0) ? PWq : (m == 1) ? PWk : PWv;
  const float* bias       = (m == 0) ? bq  : (m == 1) ? bk  : bv;
  const int cidx = nq*4 + w;          // 16-col chunk this wave owns
  f32x4 acc[2];
  #pragma unroll
  for (int a = 0; a < 2; a++){ f32x4 z = {0.f,0.f,0.f,0.f}; acc[a] = z; }
  #pragma unroll
  for (int kc = 0; kc < 8; kc++){
    bh8 bf = *(const bh8*)(P + ((size_t)(kc*16 + cidx)*64 + l)*8);
    #pragma unroll
    for (int rt = 0; rt < 2; rt++){
      bh8 af = *(const bh8*)(&Xb[(rt*16 + lm)*264 + kc*32 + q4*8]);
      acc[rt] = __builtin_amdgcn_mfma_f32_16x16x32_bf16(af, bf, acc[rt], 0, 0, 0);
    }
  }
  {
    int c = cidx*16 + lm;
    float bb = bias[c];
    #pragma unroll
    for (int rt = 0; rt < 2; rt++)
      #pragma unroll
      for (int rg = 0; rg < 4; rg++){
        int row = jb*32 + rt*16 + q4*4 + rg;
        float v = acc[rt][rg] + bb;
        if (m == 0){
          QmH[(size_t)row*CDIM + c] = f2bf(v);
          // tiled-coalesced Q^T: group = row>>2, innermost = rg
          QmT[(((size_t)(row >> 2))*CDIM + c)*4 + rg] = v;
        } else if (m == 1){
          int kc2 = c >> 5;            // head
          int jj2 = c & 7;
          int l2  = ((c >> 3) & 3)*16 + (row & 15);
          PKt[(((size_t)kc2*24 + (row >> 4))*64 + l2)*8 + jj2] = f2bf(v);
        } else {
          Vm[(size_t)row*CDIM + c] = v;
        }
      }
  }
}

// ---------------------------------------------------------------------------
// Main tile kernel: one block per (i, j-tile). 2304 blocks. R13 structure.
// R16: Sg written via 2 KB LDS tile + coalesced float2 stores at kernel end
// (was predicated 4-B scattered stores -> partial-line HBM write
// amplification, 18.1 MB observed vs 6.9 MB ideal). LDS 45568 B, still
// 3 blocks/CU.
// ---------------------------------------------------------------------------
__global__ __launch_bounds__(256, 3) void x3d_tiles(
  const float* __restrict__ x2d,
  const float* __restrict__ bpre, const float* __restrict__ ln_g, const float* __restrict__ ln_b,
  const float* __restrict__ beq,  const float* __restrict__ bek,
  const float* __restrict__ QmT,  const unsigned short* __restrict__ QmH,
  const unsigned short* __restrict__ PKt,
  const unsigned short* __restrict__ Pp, const unsigned short* __restrict__ Pq,
  const unsigned short* __restrict__ Pk,
  float* __restrict__ Sg, float* __restrict__ x2part)
{
  // EX holds X as fp32 (64x128, swizzled 16B blocks, 32768 B) during GEMM1,
  // then E as bf16 (64x264 shorts, 33792 B) for GEMM2/3.
  __shared__ __align__(16) unsigned short EX[64*264];      // 33792 B
  __shared__ float rowstat[4][64][2];                      //  2048 B
  __shared__ float muS[64], istdS[64];                     //   512 B
  __shared__ float bpreS[CDIM], gS[CDIM], bSh[CDIM], beqS[CDIM], bekS[CDIM]; // 5120 B
  __shared__ float qk1S[NH*64];                            //  2048 B
  __shared__ float scT[NH*64];                             //  2048 B (score tile)

  const int bx = blockIdx.x;
  const int i = bx / 6, jt = bx % 6, j0 = jt * 64;
  const int t = threadIdx.x;
  const int w = t >> 6, l = t & 63, q4 = l >> 4, lm = l & 15;
  const int wbase = w << 6;

  // ---- qk1 fragment loads FIRST (oldest in vmcnt queue) ----
  bh8 aqv[2], kf[2][4];
  #pragma unroll
  for (int hh = 0; hh < 2; hh++){
    int h = 2*w + hh;
    aqv[hh] = *(const bh8*)(QmH + (size_t)i*CDIM + h*HD + q4*8);
    #pragma unroll
    for (int ct = 0; ct < 4; ct++)
      kf[hh][ct] = *(const bh8*)(PKt + (((size_t)h*24 + (jt*4 + ct))*64 + l)*8);
  }

  // ---- async stage x2d tile (64x128 fp32, 32 KB) direct to LDS ----
  // LDS block P (16B) = w*512 + it*64 + l; row = P>>5, pb = P&31;
  // global source block = pb ^ (row&7)  (XOR swizzle on the global side).
  {
    const char* gtile = (const char*)(x2d + ((size_t)i*LLEN + j0)*DIN);
    #pragma unroll
    for (int it = 0; it < 8; it++){
      int P   = w*512 + it*64 + l;
      int row = P >> 5;
      int blk = (P & 31) ^ (row & 7);
      const void* gp = gtile + ((size_t)row*512 + ((size_t)blk << 4));
      unsigned short* lp = EX + (w*4096 + it*512);
      __builtin_amdgcn_global_load_lds(
          (const __attribute__((address_space(1))) void*)gp,
          (__attribute__((address_space(3))) void*)lp, 16, 0, 0);
    }
  }

  // ---- qk1 MFMAs (wait only on their own loads; staging stays in flight) ----
  #pragma unroll
  for (int hh = 0; hh < 2; hh++){
    int h = 2*w + hh;
    #pragma unroll
    for (int ct = 0; ct < 4; ct++){
      f32x4 z = {0.f,0.f,0.f,0.f};
      f32x4 a1 = __builtin_amdgcn_mfma_f32_16x16x32_bf16(aqv[hh], kf[hh][ct], z, 0, 0, 0);
      if (q4 == 0) qk1S[h*64 + ct*16 + lm] = a1[0];
    }
  }

  bpreS[t] = bpre[t]; gS[t] = ln_g[t]; bSh[t] = ln_b[t];
  beqS[t]  = beq[t];  bekS[t] = bek[t];
  __syncthreads();   // drains staging too

  // ---- GEMM1: Epre = X @ Wpre (fp32 LDS reads + cvt) ----
  const float* XF = (const float*)EX;
  f32x4 acc[4][4];
  #pragma unroll
  for (int a = 0; a < 4; a++)
    #pragma unroll
    for (int b = 0; b < 4; b++){ f32x4 z = {0.f,0.f,0.f,0.f}; acc[a][b] = z; }
  #pragma unroll
  for (int kc = 0; kc < 4; kc++){
    bh8 af[4];
    #pragma unroll
    for (int rt = 0; rt < 4; rt++){
      int row = rt*16 + lm;
      int sw  = row & 7;
      int blk0 = kc*8 + q4*2;
      f32x4 a0 = *(const f32x4*)(XF + row*128 + ((blk0       ^ sw) << 2));
      f32x4 a1 = *(const f32x4*)(XF + row*128 + (((blk0 + 1) ^ sw) << 2));
      union { unsigned int u[4]; bh8 v; } cv;
      cv.u[0] = pkbf(a0[0], a0[1]); cv.u[1] = pkbf(a0[2], a0[3]);
      cv.u[2] = pkbf(a1[0], a1[1]); cv.u[3] = pkbf(a1[2], a1[3]);
      af[rt] = cv.v;
    }
    #pragma unroll
    for (int ct = 0; ct < 4; ct++){
      bh8 bf = *(const bh8*)(Pp + ((size_t)(kc*16 + (w*4 + ct))*64 + l)*8);
      #pragma unroll
      for (int rt = 0; rt < 4; rt++)
        acc[rt][ct] = __builtin_amdgcn_mfma_f32_16x16x32_bf16(af[rt], bf, acc[rt][ct], 0, 0, 0);
    }
  }

  // ---- + bpre, per-row LN stats via packed tree-reduce ----
  #pragma unroll
  for (int rt = 0; rt < 4; rt++){
    float v[8];   // v[2rg+0]=sum partial, v[2rg+1]=sq partial
    #pragma unroll
    for (int p = 0; p < 8; p++) v[p] = 0.f;
    #pragma unroll
    for (int ct = 0; ct < 4; ct++){
      float bb = bpreS[wbase + ct*16 + lm];
      #pragma unroll
      for (int rg = 0; rg < 4; rg++){
        float x = acc[rt][ct][rg] + bb;
        acc[rt][ct][rg] = x;
        v[2*rg]   += x;
        v[2*rg+1] += x*x;
      }
    }
    float red = pk_reduce8(v, lm);
    if (lm < 8){
      int p = lm;                       // p = 2rg+which
      rowstat[w][rt*16 + q4*4 + (p >> 1)][p & 1] = red;
    }
  }
  __syncthreads();
  if (t < 64){
    float s  = rowstat[0][t][0] + rowstat[1][t][0] + rowstat[2][t][0] + rowstat[3][t][0];
    float s2 = rowstat[0][t][1] + rowstat[1][t][1] + rowstat[2][t][1] + rowstat[3][t][1];
    float mu = s * (1.f/256.f);
    float var = s2 * (1.f/256.f) - mu*mu;
    muS[t] = mu;
    istdS[t] = rsqrtf(var + LN_EPS);
  }
  __syncthreads();

  // ---- LN + ReLU -> bf16 E tile (stride 264, overwrites X) ----
  #pragma unroll
  for (int rt = 0; rt < 4; rt++){
    #pragma unroll
    for (int rg = 0; rg < 4; rg++){
      int row = rt*16 + q4*4 + rg;
      float mu = muS[row], is = istdS[row];
      #pragma unroll
      for (int ct = 0; ct < 4; ct++){
        int c = wbase + ct*16 + lm;
        float v = (acc[rt][ct][rg] - mu)*is*gS[c] + bSh[c];
        v = fmaxf(v, 0.f);
        EX[row*264 + c] = f2bf(v);
      }
    }
  }
  __syncthreads();

  // ---- GEMM2: EFK = E @ Wek ----
  #pragma unroll
  for (int a = 0; a < 4; a++)
    #pragma unroll
    for (int b = 0; b < 4; b++){ f32x4 z = {0.f,0.f,0.f,0.f}; acc[a][b] = z; }
  #pragma unroll
  for (int kc = 0; kc < 8; kc++){
    bh8 af[4];
    #pragma unroll
    for (int rt = 0; rt < 4; rt++)
      af[rt] = *(const bh8*)(&EX[(rt*16 + lm)*264 + kc*32 + q4*8]);
    #pragma unroll
    for (int ct = 0; ct < 4; ct++){
      bh8 bf = *(const bh8*)(Pk + ((size_t)(kc*16 + (w*4 + ct))*64 + l)*8);
      #pragma unroll
      for (int rt = 0; rt < 4; rt++)
        acc[rt][ct] = __builtin_amdgcn_mfma_f32_16x16x32_bf16(af[rt], bf, acc[rt][ct], 0, 0, 0);
    }
  }

  // ---- scores: term2 packed-reduce + qk1 + scale; to screg + LDS tile ----
  float screg[4];
  #pragma unroll
  for (int rt = 0; rt < 4; rt++){
    float v[8];   // v[2rg+which]
    #pragma unroll
    for (int p = 0; p < 8; p++) v[p] = 0.f;
    #pragma unroll
    for (int ct = 0; ct < 4; ct++){
      int c = wbase + ct*16 + lm;
      float bek_ = bekS[c];
      // tiled-coalesced Q^T read: group = jt*16 + rt*4 + q4, 4 j's contiguous
      float4 qv = *(const float4*)(QmT + (((size_t)jt*16 + rt*4 + q4)*CDIM + c)*4);
      int wh = ct >> 1;
      v[0 + wh] += (acc[rt][ct][0] + bek_) * qv.x;
      v[2 + wh] += (acc[rt][ct][1] + bek_) * qv.y;
      v[4 + wh] += (acc[rt][ct][2] + bek_) * qv.z;
      v[6 + wh] += (acc[rt][ct][3] + bek_) * qv.w;
    }
    float red = pk_reduce8(v, lm);
    int p = lm & 7;                     // p = 2rg + which
    int jloc = rt*16 + q4*4 + (p >> 1);
    float sc = (red + qk1S[(2*w + (p & 1))*64 + jloc]) * SCL;
    screg[rt] = sc;
    if (lm < 8)
      scT[(2*w + (p & 1))*64 + jloc] = sc;
  }

  // ---- GEMM3: EFQ = E @ Weq ----
  #pragma unroll
  for (int a = 0; a < 4; a++)
    #pragma unroll
    for (int b = 0; b < 4; b++){ f32x4 z = {0.f,0.f,0.f,0.f}; acc[a][b] = z; }
  #pragma unroll
  for (int kc = 0; kc < 8; kc++){
    bh8 af[4];
    #pragma unroll
    for (int rt = 0; rt < 4; rt++)
      af[rt] = *(const bh8*)(&EX[(rt*16 + lm)*264 + kc*32 + q4*8]);
    #pragma unroll
    for (int ct = 0; ct < 4; ct++){
      bh8 bf = *(const bh8*)(Pq + ((size_t)(kc*16 + (w*4 + ct))*64 + l)*8);
      #pragma unroll
      for (int rt = 0; rt < 4; rt++)
        acc[rt][ct] = __builtin_amdgcn_mfma_f32_16x16x32_bf16(af[rt], bf, acc[rt][ct], 0, 0, 0);
    }
  }

  // ---- x2 partial: x2[h,c] += scores[h,j]*efq[j,c] (pre-softmax scaled) ----
  float x2p[4] = {0.f, 0.f, 0.f, 0.f};
  float bq4[4];
  #pragma unroll
  for (int ct = 0; ct < 4; ct++) bq4[ct] = beqS[wbase + ct*16 + lm];
  #pragma unroll
  for (int rt = 0; rt < 4; rt++){
    float sb[8];
    #pragma unroll
    for (int p = 0; p < 8; p++)
      sb[p] = __shfl(screg[rt], (l & 48) | p, 64);
    #pragma unroll
    for (int ct = 0; ct < 4; ct++){
      int wh = ct >> 1;
      #pragma unroll
      for (int rg = 0; rg < 4; rg++)
        x2p[ct] = fmaf(sb[2*rg + wh], acc[rt][ct][rg] + bq4[ct], x2p[ct]);
    }
  }
  {
    bool b4 = l & 16, b5 = l & 32;
    float r0 = (b4 ? x2p[1] : x2p[0]) + __shfl_xor(b4 ? x2p[0] : x2p[1], 16, 64);
    float r1 = (b4 ? x2p[3] : x2p[2]) + __shfl_xor(b4 ? x2p[2] : x2p[3], 16, 64);
    float q  = (b5 ? r1 : r0) + __shfl_xor(b5 ? r0 : r1, 32, 64);
    int ctq = ((l >> 4) & 1) | (((l >> 5) & 1) << 1);
    x2part[((size_t)jt*LLEN + i)*CDIM + wbase + ctq*16 + lm] = q;
  }

  // ---- coalesced Sg write: 8 heads x 64 j, float2 per thread ----
  __syncthreads();
  {
    int h = t >> 5, jj = (t & 31) * 2;
    *(float2*)(Sg + ((size_t)i*NH + h)*LLEN + j0 + jj) =
        *(const float2*)(scT + h*64 + jj);
  }
}

// ---------------------------------------------------------------------------
// finish: R16 — 512 threads. Softmax: one full wave per head. x1: j-range
// split across thread-halves; Wo: c-range split; LDS partial-combine.
// Doubles waves/CU (6->12) and halves both serial dot-product chains.
// ---------------------------------------------------------------------------
__global__ __launch_bounds__(512) void finish(
    const float* __restrict__ Sg, const float* __restrict__ x2part,
    const float* __restrict__ Vm, const float* __restrict__ Wo,
    const float* __restrict__ bo, float* __restrict__ out)
{
  __shared__ float scoresS[NH*LLEN];   // 12 KB
  __shared__ float xoutS[CDIM];        //  1 KB
  __shared__ float part[2][CDIM];      //  2 KB
  const int i = blockIdx.x;
  const int t = threadIdx.x;

  #pragma unroll
  for (int it = 0; it < 2; it++){
    int idx = it*512 + t;
    if (idx < 768)
      ((float4*)scoresS)[idx] = ((const float4*)(Sg + (size_t)i*NH*LLEN))[idx];
  }
  __syncthreads();

  // softmax: head h = t>>6 handled by one full wave (64 lanes x 6 elems)
  {
    const int h = t >> 6, g = t & 63;
    float sv[6];
    float mx = -3.0e38f;
    #pragma unroll
    for (int it = 0; it < 6; it++){
      float s = scoresS[h*LLEN + it*64 + g];
      sv[it] = s;
      mx = fmaxf(mx, s);
    }
    #pragma unroll
    for (int mk = 1; mk < 64; mk <<= 1) mx = fmaxf(mx, __shfl_xor(mx, mk, 64));
    float den = 0.f;
    #pragma unroll
    for (int it = 0; it < 6; it++){ float e = __expf(sv[it] - mx); sv[it] = e; den += e; }
    #pragma unroll
    for (int mk = 1; mk < 64; mk <<= 1) den += __shfl_xor(den, mk, 64);
    float rden = 1.f / den;
    #pragma unroll
    for (int it = 0; it < 6; it++) scoresS[h*LLEN + it*64 + g] = sv[it]*rden;
  }
  __syncthreads();

  const int tc = t & 255;       // output channel
  const int jh = t >> 8;        // which half of the j/c range
  const int h2 = tc >> 5;       // head of this channel

  // x1 partial over j in [jh*192, jh*192+192), plus half of the x2v sum
  float a[8];
  #pragma unroll
  for (int k = 0; k < 8; k++) a[k] = 0.f;
  {
    const float* vp = Vm + tc;
    const float* sp = scoresS + h2*LLEN + jh*192;
    const size_t voff = (size_t)jh*192*CDIM;
    #pragma unroll 2
    for (int j = 0; j < 192; j += 8){
      #pragma unroll
      for (int k = 0; k < 8; k++)
        a[k] = fmaf(sp[j+k], vp[voff + (size_t)(j+k)*CDIM], a[k]);
    }
  }
  float x1 = ((a[0]+a[1]) + (a[2]+a[3])) + ((a[4]+a[5]) + (a[6]+a[7]));
  float x2v = 0.f;
  #pragma unroll
  for (int q = 0; q < 3; q++)
    x2v += x2part[((size_t)(jh*3 + q)*LLEN + i)*CDIM + tc];
  part[jh][tc] = x1 + x2v;
  __syncthreads();
  if (t < 256) xoutS[t] = part[0][t] + part[1][t];
  __syncthreads();

  // Wo partial over c in [jh*128, jh*128+128)
  float b0a = (jh == 0) ? bo[tc] : 0.f, b1a = 0.f, b2a = 0.f, b3a = 0.f;
  {
    const int c0 = jh*128;
    #pragma unroll 4
    for (int c = 0; c < 128; c += 4){
      b0a = fmaf(xoutS[c0+c+0], Wo[(size_t)(c0+c+0)*CDIM + tc], b0a);
      b1a = fmaf(xoutS[c0+c+1], Wo[(size_t)(c0+c+1)*CDIM + tc], b1a);
      b2a = fmaf(xoutS[c0+c+2], Wo[(size_t)(c0+c+2)*CDIM + tc], b2a);
      b3a = fmaf(xoutS[c0+c+3], Wo[(size_t)(c0+c+3)*CDIM + tc], b3a);
    }
  }
  __syncthreads();   // xoutS reads done before part[] overwrite
  part[jh][tc] = (b0a + b1a) + (b2a + b3a);
  __syncthreads();
  if (t < 256) out[(size_t)i*CDIM + t] = part[0][t] + part[1][t];
}

// ---------------------------------------------------------------------------
extern "C" void kernel_launch(void* const* d_in, const int* in_sizes, int n_in,
                              void* d_out, int out_size, void* d_ws, size_t ws_size,
                              hipStream_t stream)
{
  const float* x2d  = (const float*)d_in[0];
  const float* x3d  = (const float*)d_in[1];
  const float* Wq   = (const float*)d_in[2];
  const float* bq   = (const float*)d_in[3];
  const float* Wk   = (const float*)d_in[4];
  const float* bk   = (const float*)d_in[5];
  const float* Wv   = (const float*)d_in[6];
  const float* bv   = (const float*)d_in[7];
  const float* Wpre = (const float*)d_in[8];
  const float* bpre = (const float*)d_in[9];
  const float* ln_g = (const float*)d_in[10];
  const float* ln_b = (const float*)d_in[11];
  const float* Weq  = (const float*)d_in[12];
  const float* beq  = (const float*)d_in[13];
  const float* Wek  = (const float*)d_in[14];
  const float* bek  = (const float*)d_in[15];
  const float* Wo   = (const float*)d_in[16];
  const float* bo   = (const float*)d_in[17];
  float* out = (float*)d_out;

  float* Vm  = (float*)d_ws;                                 // 384*256 f32
  float* QmT = Vm + LLEN*CDIM;                               // 96*256*4 f32 (tiled Q^T)
  unsigned short* QmH = (unsigned short*)(QmT + CDIM*LLEN);  // 384*256 bf16
  unsigned short* PKt = QmH + LLEN*CDIM;                     // 8*24*64*8 bf16
  unsigned short* Pp  = PKt + LLEN*CDIM;                     // 128*256
  unsigned short* Pq  = Pp  + DIN*CDIM;                      // 256*256
  unsigned short* Pk  = Pq  + CDIM*CDIM;
  unsigned short* PWq = Pk  + CDIM*CDIM;
  unsigned short* PWk = PWq + CDIM*CDIM;
  unsigned short* PWv = PWk + CDIM*CDIM;
  float* Sg     = (float*)(PWv + CDIM*CDIM);                 // 384*8*384 f32
  float* x2part = Sg + (size_t)LLEN*NH*LLEN;                 // 6*384*256 f32

  pack_w<<<dim3(176), dim3(256), 0, stream>>>(Wpre, Weq, Wek, Wq, Wk, Wv,
                                              Pp, Pq, Pk, PWq, PWk, PWv);
  qkv_mfma<<<dim3(144), dim3(256), 0, stream>>>(x3d, bq, bk, bv, PWq, PWk, PWv,
                                                Vm, QmH, QmT, PKt);
  x3d_tiles<<<dim3(LLEN*6), dim3(256), 0, stream>>>(x2d, bpre, ln_g, ln_b, beq, bek,
                                                    QmT, QmH, PKt, Pp, Pq, Pk, Sg, x2part);
  finish<<<dim3(LLEN), dim3(512), 0, stream>>>(Sg, x2part, Vm, Wo, bo, out);
}

// Round 9
// 209.531 us; speedup vs baseline: 1.0469x; 1.0168x over previous
//
#include <hip/hip_runtime.h>
#include <hip/hip_bf16.h>

#define LLEN 384
#define CDIM 256
#define NH 8
#define HD 32
#define DIN 128
#define LN_EPS 1e-5f
#define SCL 0.17677669529663687f   // 1/sqrt(32)

typedef __attribute__((ext_vector_type(8))) short bh8;
typedef __attribute__((ext_vector_type(4))) float f32x4;
typedef __attribute__((ext_vector_type(4))) unsigned int u32x4;

__device__ __forceinline__ unsigned short f2bf(float f){
  unsigned int u = __float_as_uint(f);
  u += 0x7fffu + ((u >> 16) & 1u);
  return (unsigned short)(u >> 16);
}

// Pack two fp32 -> dword of 2 bf16 (RNE). HW v_cvt_pk_bf16_f32 on gfx950.
__device__ __forceinline__ unsigned int pkbf(float a, float b){
#if defined(__gfx950__) && __has_builtin(__builtin_amdgcn_cvt_pk_bf16_f32)
  typedef __attribute__((ext_vector_type(2))) __bf16 vbf2;
  vbf2 v = __builtin_amdgcn_cvt_pk_bf16_f32(a, b);
  union { vbf2 v; unsigned int u; } cv; cv.v = v; return cv.u;
#else
  return (unsigned int)f2bf(a) | ((unsigned int)f2bf(b) << 16);
#endif
}

// Packed tree-reduce: sum v[0..7] over the 16 lanes of a quad (lane bits 0-3).
// Returns: lane lm holds full sum of v[lm&7].
__device__ __forceinline__ float pk_reduce8(const float* v, int lane){
  bool b0 = lane & 1, b1 = lane & 2, b2 = lane & 4;
  float r0 = (b0 ? v[1] : v[0]) + __shfl_xor(b0 ? v[0] : v[1], 1, 64);
  float r1 = (b0 ? v[3] : v[2]) + __shfl_xor(b0 ? v[2] : v[3], 1, 64);
  float r2 = (b0 ? v[5] : v[4]) + __shfl_xor(b0 ? v[4] : v[5], 1, 64);
  float r3 = (b0 ? v[7] : v[6]) + __shfl_xor(b0 ? v[6] : v[7], 1, 64);
  float s0 = (b1 ? r1 : r0) + __shfl_xor(b1 ? r0 : r1, 2, 64);
  float s1 = (b1 ? r3 : r2) + __shfl_xor(b1 ? r2 : r3, 2, 64);
  float t0 = (b2 ? s1 : s0) + __shfl_xor(b2 ? s0 : s1, 4, 64);
  return t0 + __shfl_xor(t0, 8, 64);
}

// ---------------------------------------------------------------------------
// Pack weights (fp32 row-major [K][N]) into bf16 MFMA B-fragment order.
// ---------------------------------------------------------------------------
__global__ __launch_bounds__(256) void pack_w(
    const float* __restrict__ Wpre, const float* __restrict__ Weq,
    const float* __restrict__ Wek,  const float* __restrict__ Wq,
    const float* __restrict__ Wk,   const float* __restrict__ Wv,
    unsigned short* __restrict__ Pp, unsigned short* __restrict__ Pq,
    unsigned short* __restrict__ Pk, unsigned short* __restrict__ PWq,
    unsigned short* __restrict__ PWk, unsigned short* __restrict__ PWv)
{
  int tid = blockIdx.x * 256 + threadIdx.x;   // 176 blocks * 256 = 45056
  const float* W; unsigned short* P; int base;
  if      (tid <  4096){ W = Wpre; P = Pp;  base = tid;         }
  else if (tid < 12288){ W = Weq;  P = Pq;  base = tid -  4096; }
  else if (tid < 20480){ W = Wek;  P = Pk;  base = tid - 12288; }
  else if (tid < 28672){ W = Wq;   P = PWq; base = tid - 20480; }
  else if (tid < 36864){ W = Wk;   P = PWk; base = tid - 28672; }
  else                 { W = Wv;   P = PWv; base = tid - 36864; }
  int l   = base & 63;
  int c   = (base >> 6) & 15;
  int kc  = base >> 10;
  int krow = kc*32 + (l >> 4)*8;
  int col  = c*16 + (l & 15);
  unsigned int wds[4];
  #pragma unroll
  for (int p = 0; p < 4; p++){
    unsigned short lo = f2bf(W[(size_t)(krow + 2*p    )*CDIM + col]);
    unsigned short hi = f2bf(W[(size_t)(krow + 2*p + 1)*CDIM + col]);
    wds[p] = (unsigned int)lo | ((unsigned int)hi << 16);
  }
  uint4 v; v.x = wds[0]; v.y = wds[1]; v.z = wds[2]; v.w = wds[3];
  *(uint4*)(P + (size_t)base*8) = v;
}

// ---------------------------------------------------------------------------
// qkv: 144 blocks = jb(12, 32-row tiles) x m(3) x nq(4).
// ---------------------------------------------------------------------------
__global__ __launch_bounds__(256) void qkv_mfma(
    const float* __restrict__ x3d,
    const float* __restrict__ bq, const float* __restrict__ bk, const float* __restrict__ bv,
    const unsigned short* __restrict__ PWq, const unsigned short* __restrict__ PWk,
    const unsigned short* __restrict__ PWv,
    float* __restrict__ Vm, unsigned short* __restrict__ QmH,
    float* __restrict__ QmT, unsigned short* __restrict__ PKt)
{
  __shared__ __align__(16) unsigned short Xb[32*264];
  const int bx = blockIdx.x;
  const int jb = bx / 12, rem = bx % 12;
  const int m = rem >> 2, nq = rem & 3;
  const int t  = threadIdx.x;
  const int w  = t >> 6, l = t & 63, q4 = l >> 4, lm = l & 15;

  const float* src = x3d + (size_t)jb*32*CDIM;
  #pragma unroll
  for (int it = 0; it < 8; it++){
    int idx = it*256 + t;
    int r = idx >> 6, k4 = (idx & 63) << 2;
    float4 v = *(const float4*)(src + (size_t)r*CDIM + k4);
    ushort4 b;
    b.x = f2bf(v.x); b.y = f2bf(v.y); b.z = f2bf(v.z); b.w = f2bf(v.w);
    *(ushort4*)(&Xb[r*264 + k4]) = b;
  }
  __syncthreads();

  const unsigned short* P = (m == 0) ? PWq : (m == 1) ? PWk : PWv;
  const float* bias       = (m == 0) ? bq  : (m == 1) ? bk  : bv;
  const int cidx = nq*4 + w;          // 16-col chunk this wave owns
  f32x4 acc[2];
  #pragma unroll
  for (int a = 0; a < 2; a++){ f32x4 z = {0.f,0.f,0.f,0.f}; acc[a] = z; }
  #pragma unroll
  for (int kc = 0; kc < 8; kc++){
    bh8 bf = *(const bh8*)(P + ((size_t)(kc*16 + cidx)*64 + l)*8);
    #pragma unroll
    for (int rt = 0; rt < 2; rt++){
      bh8 af = *(const bh8*)(&Xb[(rt*16 + lm)*264 + kc*32 + q4*8]);
      acc[rt] = __builtin_amdgcn_mfma_f32_16x16x32_bf16(af, bf, acc[rt], 0, 0, 0);
    }
  }
  {
    int c = cidx*16 + lm;
    float bb = bias[c];
    #pragma unroll
    for (int rt = 0; rt < 2; rt++)
      #pragma unroll
      for (int rg = 0; rg < 4; rg++){
        int row = jb*32 + rt*16 + q4*4 + rg;
        float v = acc[rt][rg] + bb;
        if (m == 0){
          QmH[(size_t)row*CDIM + c] = f2bf(v);
          // tiled-coalesced Q^T: group = row>>2, innermost = rg
          QmT[(((size_t)(row >> 2))*CDIM + c)*4 + rg] = v;
        } else if (m == 1){
          int kc2 = c >> 5;            // head
          int jj2 = c & 7;
          int l2  = ((c >> 3) & 3)*16 + (row & 15);
          PKt[(((size_t)kc2*24 + (row >> 4))*64 + l2)*8 + jj2] = f2bf(v);
        } else {
          Vm[(size_t)row*CDIM + c] = v;
        }
      }
  }
}

// ---------------------------------------------------------------------------
// Main tile kernel: one block per (i, j-tile). 2304 blocks. EXACT R15 body
// (83 us proven). R17 lesson: the 18 MB WRITE_SIZE is a SYMPTOM of the fast
// schedule (partial-line L2 evictions), not a cost — "fixing" it via an LDS
// score tile + tail barrier (R16) cost 24 us. Scattered mid-phase Sg stores
// restored; no tail barrier.
// ---------------------------------------------------------------------------
__global__ __launch_bounds__(256, 3) void x3d_tiles(
  const float* __restrict__ x2d,
  const float* __restrict__ bpre, const float* __restrict__ ln_g, const float* __restrict__ ln_b,
  const float* __restrict__ beq,  const float* __restrict__ bek,
  const float* __restrict__ QmT,  const unsigned short* __restrict__ QmH,
  const unsigned short* __restrict__ PKt,
  const unsigned short* __restrict__ Pp, const unsigned short* __restrict__ Pq,
  const unsigned short* __restrict__ Pk,
  float* __restrict__ Sg, float* __restrict__ x2part)
{
  // EX holds X as fp32 (64x128, swizzled 16B blocks, 32768 B) during GEMM1,
  // then E as bf16 (64x264 shorts, 33792 B) for GEMM2/3.
  __shared__ __align__(16) unsigned short EX[64*264];      // 33792 B
  __shared__ float rowstat[4][64][2];                      //  2048 B
  __shared__ float muS[64], istdS[64];                     //   512 B
  __shared__ float bpreS[CDIM], gS[CDIM], bSh[CDIM], beqS[CDIM], bekS[CDIM]; // 5120 B
  __shared__ float qk1S[NH*64];                            //  2048 B

  const int bx = blockIdx.x;
  const int i = bx / 6, jt = bx % 6, j0 = jt * 64;
  const int t = threadIdx.x;
  const int w = t >> 6, l = t & 63, q4 = l >> 4, lm = l & 15;
  const int wbase = w << 6;

  // ---- qk1 fragment loads FIRST (oldest in vmcnt queue) ----
  bh8 aqv[2], kf[2][4];
  #pragma unroll
  for (int hh = 0; hh < 2; hh++){
    int h = 2*w + hh;
    aqv[hh] = *(const bh8*)(QmH + (size_t)i*CDIM + h*HD + q4*8);
    #pragma unroll
    for (int ct = 0; ct < 4; ct++)
      kf[hh][ct] = *(const bh8*)(PKt + (((size_t)h*24 + (jt*4 + ct))*64 + l)*8);
  }

  // ---- async stage x2d tile (64x128 fp32, 32 KB) direct to LDS ----
  // LDS block P (16B) = w*512 + it*64 + l; row = P>>5, pb = P&31;
  // global source block = pb ^ (row&7)  (XOR swizzle on the global side).
  {
    const char* gtile = (const char*)(x2d + ((size_t)i*LLEN + j0)*DIN);
    #pragma unroll
    for (int it = 0; it < 8; it++){
      int P   = w*512 + it*64 + l;
      int row = P >> 5;
      int blk = (P & 31) ^ (row & 7);
      const void* gp = gtile + ((size_t)row*512 + ((size_t)blk << 4));
      unsigned short* lp = EX + (w*4096 + it*512);
      __builtin_amdgcn_global_load_lds(
          (const __attribute__((address_space(1))) void*)gp,
          (__attribute__((address_space(3))) void*)lp, 16, 0, 0);
    }
  }

  // ---- qk1 MFMAs (wait only on their own loads; staging stays in flight) ----
  #pragma unroll
  for (int hh = 0; hh < 2; hh++){
    int h = 2*w + hh;
    #pragma unroll
    for (int ct = 0; ct < 4; ct++){
      f32x4 z = {0.f,0.f,0.f,0.f};
      f32x4 a1 = __builtin_amdgcn_mfma_f32_16x16x32_bf16(aqv[hh], kf[hh][ct], z, 0, 0, 0);
      if (q4 == 0) qk1S[h*64 + ct*16 + lm] = a1[0];
    }
  }

  bpreS[t] = bpre[t]; gS[t] = ln_g[t]; bSh[t] = ln_b[t];
  beqS[t]  = beq[t];  bekS[t] = bek[t];
  __syncthreads();   // drains staging too

  // ---- GEMM1: Epre = X @ Wpre (fp32 LDS reads + cvt) ----
  const float* XF = (const float*)EX;
  f32x4 acc[4][4];
  #pragma unroll
  for (int a = 0; a < 4; a++)
    #pragma unroll
    for (int b = 0; b < 4; b++){ f32x4 z = {0.f,0.f,0.f,0.f}; acc[a][b] = z; }
  #pragma unroll
  for (int kc = 0; kc < 4; kc++){
    bh8 af[4];
    #pragma unroll
    for (int rt = 0; rt < 4; rt++){
      int row = rt*16 + lm;
      int sw  = row & 7;
      int blk0 = kc*8 + q4*2;
      f32x4 a0 = *(const f32x4*)(XF + row*128 + ((blk0       ^ sw) << 2));
      f32x4 a1 = *(const f32x4*)(XF + row*128 + (((blk0 + 1) ^ sw) << 2));
      union { unsigned int u[4]; bh8 v; } cv;
      cv.u[0] = pkbf(a0[0], a0[1]); cv.u[1] = pkbf(a0[2], a0[3]);
      cv.u[2] = pkbf(a1[0], a1[1]); cv.u[3] = pkbf(a1[2], a1[3]);
      af[rt] = cv.v;
    }
    #pragma unroll
    for (int ct = 0; ct < 4; ct++){
      bh8 bf = *(const bh8*)(Pp + ((size_t)(kc*16 + (w*4 + ct))*64 + l)*8);
      #pragma unroll
      for (int rt = 0; rt < 4; rt++)
        acc[rt][ct] = __builtin_amdgcn_mfma_f32_16x16x32_bf16(af[rt], bf, acc[rt][ct], 0, 0, 0);
    }
  }

  // ---- + bpre, per-row LN stats via packed tree-reduce ----
  #pragma unroll
  for (int rt = 0; rt < 4; rt++){
    float v[8];   // v[2rg+0]=sum partial, v[2rg+1]=sq partial
    #pragma unroll
    for (int p = 0; p < 8; p++) v[p] = 0.f;
    #pragma unroll
    for (int ct = 0; ct < 4; ct++){
      float bb = bpreS[wbase + ct*16 + lm];
      #pragma unroll
      for (int rg = 0; rg < 4; rg++){
        float x = acc[rt][ct][rg] + bb;
        acc[rt][ct][rg] = x;
        v[2*rg]   += x;
        v[2*rg+1] += x*x;
      }
    }
    float red = pk_reduce8(v, lm);
    if (lm < 8){
      int p = lm;                       // p = 2rg+which
      rowstat[w][rt*16 + q4*4 + (p >> 1)][p & 1] = red;
    }
  }
  __syncthreads();
  if (t < 64){
    float s  = rowstat[0][t][0] + rowstat[1][t][0] + rowstat[2][t][0] + rowstat[3][t][0];
    float s2 = rowstat[0][t][1] + rowstat[1][t][1] + rowstat[2][t][1] + rowstat[3][t][1];
    float mu = s * (1.f/256.f);
    float var = s2 * (1.f/256.f) - mu*mu;
    muS[t] = mu;
    istdS[t] = rsqrtf(var + LN_EPS);
  }
  __syncthreads();

  // ---- LN + ReLU -> bf16 E tile (stride 264, overwrites X) ----
  #pragma unroll
  for (int rt = 0; rt < 4; rt++){
    #pragma unroll
    for (int rg = 0; rg < 4; rg++){
      int row = rt*16 + q4*4 + rg;
      float mu = muS[row], is = istdS[row];
      #pragma unroll
      for (int ct = 0; ct < 4; ct++){
        int c = wbase + ct*16 + lm;
        float v = (acc[rt][ct][rg] - mu)*is*gS[c] + bSh[c];
        v = fmaxf(v, 0.f);
        EX[row*264 + c] = f2bf(v);
      }
    }
  }
  __syncthreads();

  // ---- GEMM2: EFK = E @ Wek ----
  #pragma unroll
  for (int a = 0; a < 4; a++)
    #pragma unroll
    for (int b = 0; b < 4; b++){ f32x4 z = {0.f,0.f,0.f,0.f}; acc[a][b] = z; }
  #pragma unroll
  for (int kc = 0; kc < 8; kc++){
    bh8 af[4];
    #pragma unroll
    for (int rt = 0; rt < 4; rt++)
      af[rt] = *(const bh8*)(&EX[(rt*16 + lm)*264 + kc*32 + q4*8]);
    #pragma unroll
    for (int ct = 0; ct < 4; ct++){
      bh8 bf = *(const bh8*)(Pk + ((size_t)(kc*16 + (w*4 + ct))*64 + l)*8);
      #pragma unroll
      for (int rt = 0; rt < 4; rt++)
        acc[rt][ct] = __builtin_amdgcn_mfma_f32_16x16x32_bf16(af[rt], bf, acc[rt][ct], 0, 0, 0);
    }
  }

  // ---- scores: term2 packed-reduce + qk1 + scale; keep in screg ----
  float screg[4];
  #pragma unroll
  for (int rt = 0; rt < 4; rt++){
    float v[8];   // v[2rg+which]
    #pragma unroll
    for (int p = 0; p < 8; p++) v[p] = 0.f;
    #pragma unroll
    for (int ct = 0; ct < 4; ct++){
      int c = wbase + ct*16 + lm;
      float bek_ = bekS[c];
      // tiled-coalesced Q^T read: group = jt*16 + rt*4 + q4, 4 j's contiguous
      float4 qv = *(const float4*)(QmT + (((size_t)jt*16 + rt*4 + q4)*CDIM + c)*4);
      int wh = ct >> 1;
      v[0 + wh] += (acc[rt][ct][0] + bek_) * qv.x;
      v[2 + wh] += (acc[rt][ct][1] + bek_) * qv.y;
      v[4 + wh] += (acc[rt][ct][2] + bek_) * qv.z;
      v[6 + wh] += (acc[rt][ct][3] + bek_) * qv.w;
    }
    float red = pk_reduce8(v, lm);
    int p = lm & 7;                     // p = 2rg + which
    int jloc = rt*16 + q4*4 + (p >> 1);
    float sc = (red + qk1S[(2*w + (p & 1))*64 + jloc]) * SCL;
    screg[rt] = sc;
    if (lm < 8)
      Sg[((size_t)i*NH + 2*w + (p & 1))*LLEN + j0 + jloc] = sc;
  }

  // ---- GEMM3: EFQ = E @ Weq ----
  #pragma unroll
  for (int a = 0; a < 4; a++)
    #pragma unroll
    for (int b = 0; b < 4; b++){ f32x4 z = {0.f,0.f,0.f,0.f}; acc[a][b] = z; }
  #pragma unroll
  for (int kc = 0; kc < 8; kc++){
    bh8 af[4];
    #pragma unroll
    for (int rt = 0; rt < 4; rt++)
      af[rt] = *(const bh8*)(&EX[(rt*16 + lm)*264 + kc*32 + q4*8]);
    #pragma unroll
    for (int ct = 0; ct < 4; ct++){
      bh8 bf = *(const bh8*)(Pq + ((size_t)(kc*16 + (w*4 + ct))*64 + l)*8);
      #pragma unroll
      for (int rt = 0; rt < 4; rt++)
        acc[rt][ct] = __builtin_amdgcn_mfma_f32_16x16x32_bf16(af[rt], bf, acc[rt][ct], 0, 0, 0);
    }
  }

  // ---- x2 partial: x2[h,c] += scores[h,j]*efq[j,c] (pre-softmax scaled) ----
  float x2p[4] = {0.f, 0.f, 0.f, 0.f};
  float bq4[4];
  #pragma unroll
  for (int ct = 0; ct < 4; ct++) bq4[ct] = beqS[wbase + ct*16 + lm];
  #pragma unroll
  for (int rt = 0; rt < 4; rt++){
    float sb[8];
    #pragma unroll
    for (int p = 0; p < 8; p++)
      sb[p] = __shfl(screg[rt], (l & 48) | p, 64);
    #pragma unroll
    for (int ct = 0; ct < 4; ct++){
      int wh = ct >> 1;
      #pragma unroll
      for (int rg = 0; rg < 4; rg++)
        x2p[ct] = fmaf(sb[2*rg + wh], acc[rt][ct][rg] + bq4[ct], x2p[ct]);
    }
  }
  {
    bool b4 = l & 16, b5 = l & 32;
    float r0 = (b4 ? x2p[1] : x2p[0]) + __shfl_xor(b4 ? x2p[0] : x2p[1], 16, 64);
    float r1 = (b4 ? x2p[3] : x2p[2]) + __shfl_xor(b4 ? x2p[2] : x2p[3], 16, 64);
    float q  = (b5 ? r1 : r0) + __shfl_xor(b5 ? r0 : r1, 32, 64);
    int ctq = ((l >> 4) & 1) | (((l >> 5) & 1) << 1);
    x2part[((size_t)jt*LLEN + i)*CDIM + wbase + ctq*16 + lm] = q;
  }
}

// ---------------------------------------------------------------------------
// finish: 512 threads (R16 win, kept). Softmax: one full wave per head.
// x1: j-range split across thread-halves; Wo: c-range split; LDS combine.
// ---------------------------------------------------------------------------
__global__ __launch_bounds__(512) void finish(
    const float* __restrict__ Sg, const float* __restrict__ x2part,
    const float* __restrict__ Vm, const float* __restrict__ Wo,
    const float* __restrict__ bo, float* __restrict__ out)
{
  __shared__ float scoresS[NH*LLEN];   // 12 KB
  __shared__ float xoutS[CDIM];        //  1 KB
  __shared__ float part[2][CDIM];      //  2 KB
  const int i = blockIdx.x;
  const int t = threadIdx.x;

  #pragma unroll
  for (int it = 0; it < 2; it++){
    int idx = it*512 + t;
    if (idx < 768)
      ((float4*)scoresS)[idx] = ((const float4*)(Sg + (size_t)i*NH*LLEN))[idx];
  }
  __syncthreads();

  // softmax: head h = t>>6 handled by one full wave (64 lanes x 6 elems)
  {
    const int h = t >> 6, g = t & 63;
    float sv[6];
    float mx = -3.0e38f;
    #pragma unroll
    for (int it = 0; it < 6; it++){
      float s = scoresS[h*LLEN + it*64 + g];
      sv[it] = s;
      mx = fmaxf(mx, s);
    }
    #pragma unroll
    for (int mk = 1; mk < 64; mk <<= 1) mx = fmaxf(mx, __shfl_xor(mx, mk, 64));
    float den = 0.f;
    #pragma unroll
    for (int it = 0; it < 6; it++){ float e = __expf(sv[it] - mx); sv[it] = e; den += e; }
    #pragma unroll
    for (int mk = 1; mk < 64; mk <<= 1) den += __shfl_xor(den, mk, 64);
    float rden = 1.f / den;
    #pragma unroll
    for (int it = 0; it < 6; it++) scoresS[h*LLEN + it*64 + g] = sv[it]*rden;
  }
  __syncthreads();

  const int tc = t & 255;       // output channel
  const int jh = t >> 8;        // which half of the j/c range
  const int h2 = tc >> 5;       // head of this channel

  // x1 partial over j in [jh*192, jh*192+192), plus half of the x2v sum
  float a[8];
  #pragma unroll
  for (int k = 0; k < 8; k++) a[k] = 0.f;
  {
    const float* vp = Vm + tc;
    const float* sp = scoresS + h2*LLEN + jh*192;
    const size_t voff = (size_t)jh*192*CDIM;
    #pragma unroll 2
    for (int j = 0; j < 192; j += 8){
      #pragma unroll
      for (int k = 0; k < 8; k++)
        a[k] = fmaf(sp[j+k], vp[voff + (size_t)(j+k)*CDIM], a[k]);
    }
  }
  float x1 = ((a[0]+a[1]) + (a[2]+a[3])) + ((a[4]+a[5]) + (a[6]+a[7]));
  float x2v = 0.f;
  #pragma unroll
  for (int q = 0; q < 3; q++)
    x2v += x2part[((size_t)(jh*3 + q)*LLEN + i)*CDIM + tc];
  part[jh][tc] = x1 + x2v;
  __syncthreads();
  if (t < 256) xoutS[t] = part[0][t] + part[1][t];
  __syncthreads();

  // Wo partial over c in [jh*128, jh*128+128)
  float b0a = (jh == 0) ? bo[tc] : 0.f, b1a = 0.f, b2a = 0.f, b3a = 0.f;
  {
    const int c0 = jh*128;
    #pragma unroll 4
    for (int c = 0; c < 128; c += 4){
      b0a = fmaf(xoutS[c0+c+0], Wo[(size_t)(c0+c+0)*CDIM + tc], b0a);
      b1a = fmaf(xoutS[c0+c+1], Wo[(size_t)(c0+c+1)*CDIM + tc], b1a);
      b2a = fmaf(xoutS[c0+c+2], Wo[(size_t)(c0+c+2)*CDIM + tc], b2a);
      b3a = fmaf(xoutS[c0+c+3], Wo[(size_t)(c0+c+3)*CDIM + tc], b3a);
    }
  }
  __syncthreads();   // xoutS reads done before part[] overwrite
  part[jh][tc] = (b0a + b1a) + (b2a + b3a);
  __syncthreads();
  if (t < 256) out[(size_t)i*CDIM + t] = part[0][t] + part[1][t];
}

// ---------------------------------------------------------------------------
extern "C" void kernel_launch(void* const* d_in, const int* in_sizes, int n_in,
                              void* d_out, int out_size, void* d_ws, size_t ws_size,
                              hipStream_t stream)
{
  const float* x2d  = (const float*)d_in[0];
  const float* x3d  = (const float*)d_in[1];
  const float* Wq   = (const float*)d_in[2];
  const float* bq   = (const float*)d_in[3];
  const float* Wk   = (const float*)d_in[4];
  const float* bk   = (const float*)d_in[5];
  const float* Wv   = (const float*)d_in[6];
  const float* bv   = (const float*)d_in[7];
  const float* Wpre = (const float*)d_in[8];
  const float* bpre = (const float*)d_in[9];
  const float* ln_g = (const float*)d_in[10];
  const float* ln_b = (const float*)d_in[11];
  const float* Weq  = (const float*)d_in[12];
  const float* beq  = (const float*)d_in[13];
  const float* Wek  = (const float*)d_in[14];
  const float* bek  = (const float*)d_in[15];
  const float* Wo   = (const float*)d_in[16];
  const float* bo   = (const float*)d_in[17];
  float* out = (float*)d_out;

  float* Vm  = (float*)d_ws;                                 // 384*256 f32
  float* QmT = Vm + LLEN*CDIM;                               // 96*256*4 f32 (tiled Q^T)
  unsigned short* QmH = (unsigned short*)(QmT + CDIM*LLEN);  // 384*256 bf16
  unsigned short* PKt = QmH + LLEN*CDIM;                     // 8*24*64*8 bf16
  unsigned short* Pp  = PKt + LLEN*CDIM;                     // 128*256
  unsigned short* Pq  = Pp  + DIN*CDIM;                      // 256*256
  unsigned short* Pk  = Pq  + CDIM*CDIM;
  unsigned short* PWq = Pk  + CDIM*CDIM;
  unsigned short* PWk = PWq + CDIM*CDIM;
  unsigned short* PWv = PWk + CDIM*CDIM;
  float* Sg     = (float*)(PWv + CDIM*CDIM);                 // 384*8*384 f32
  float* x2part = Sg + (size_t)LLEN*NH*LLEN;                 // 6*384*256 f32

  pack_w<<<dim3(176), dim3(256), 0, stream>>>(Wpre, Weq, Wek, Wq, Wk, Wv,
                                              Pp, Pq, Pk, PWq, PWk, PWv);
  qkv_mfma<<<dim3(144), dim3(256), 0, stream>>>(x3d, bq, bk, bv, PWq, PWk, PWv,
                                                Vm, QmH, QmT, PKt);
  x3d_tiles<<<dim3(LLEN*6), dim3(256), 0, stream>>>(x2d, bpre, ln_g, ln_b, beq, bek,
                                                    QmT, QmH, PKt, Pp, Pq, Pk, Sg, x2part);
  finish<<<dim3(LLEN), dim3(512), 0, stream>>>(Sg, x2part, Vm, Wo, bo, out);
}